// Round 6
// baseline (237.434 us; speedup 1.0000x reference)
//
#include <hip/hip_runtime.h>
#include <hip/hip_bf16.h>
#include <math.h>

typedef __bf16 bf16x8 __attribute__((ext_vector_type(8)));
typedef float  f32x4  __attribute__((ext_vector_type(4)));
typedef unsigned short ushort_t;
typedef unsigned char  u8;
typedef unsigned int   u32;

#define N_POI 4096
#define NB    8
#define NDAYS 4
#define LSEQ  64
#define NROWS 32   // NB*NDAYS
#define NBINS 102  // 101 intervals + 1 pad/clamp slot
#define KCMAX 7    // split-K width cap (runtime KCr is ws-limited, ~3)

static __device__ __forceinline__ u32 bf16bits(float f) {
  u32 x = __float_as_uint(f);
  return ((x + 0x7FFFu + ((x >> 16) & 1u)) >> 16) & 0xFFFFu;  // RTNE
}

// ---------------------------------------------------------------------------
// K1: fused bucketize + per-sample setup.
// Blocks [0,2048): 2 dm rows each -> uint8 buckets (side='right' == floor(2v)+1)
//   written as uint4 (16 bytes/thread), + per-row histograms (transposed).
// Blocks [2048, 2048+NB): per-sample argsort/spans/bincount weight tables.
// ---------------------------------------------------------------------------
__global__ __launch_bounds__(256) void k_bucket_sample(
    const float* __restrict__ dm, u8* __restrict__ bucket,
    float* __restrict__ hist, const int* __restrict__ ids,
    const int* __restrict__ seq, float* __restrict__ tfp,
    u32* __restrict__ tbu, int* __restrict__ meta) {
  const int tid = threadIdx.x;
  if (blockIdx.x < 2048) {
    const int row0 = blockIdx.x * 2;
    __shared__ int h[2][NBINS];
    for (int k = tid; k < 2 * NBINS; k += 256) ((int*)h)[k] = 0;
    __syncthreads();
#pragma unroll
    for (int r = 0; r < 2; ++r) {
      const float4* drow = (const float4*)(dm + (size_t)(row0 + r) * N_POI);
      uint4* brow = (uint4*)(bucket + (size_t)(row0 + r) * N_POI);
      const int j4 = tid * 4;  // this thread: 16 consecutive elements
      const float4 v0 = drow[j4];
      const float4 v1 = drow[j4 + 1];
      const float4 v2 = drow[j4 + 2];
      const float4 v3 = drow[j4 + 3];
      u32 wq[4];
      const float4 vv[4] = {v0, v1, v2, v3};
#pragma unroll
      for (int q = 0; q < 4; ++q) {
        const int b0 = min((int)(2.0f * vv[q].x) + 1, 101);
        const int b1 = min((int)(2.0f * vv[q].y) + 1, 101);
        const int b2 = min((int)(2.0f * vv[q].z) + 1, 101);
        const int b3 = min((int)(2.0f * vv[q].w) + 1, 101);
        atomicAdd(&h[r][b0], 1); atomicAdd(&h[r][b1], 1);
        atomicAdd(&h[r][b2], 1); atomicAdd(&h[r][b3], 1);
        wq[q] = (u32)b0 | ((u32)b1 << 8) | ((u32)b2 << 16) | ((u32)b3 << 24);
      }
      uint4 pk = {wq[0], wq[1], wq[2], wq[3]};
      brow[tid] = pk;
    }
    __syncthreads();
    for (int k = tid; k < NBINS; k += 256) {
      hist[(size_t)k * N_POI + row0]     = (float)h[0][k];
      hist[(size_t)k * N_POI + row0 + 1] = (float)h[1][k];
    }
  } else {
    const int s = blockIdx.x - 2048;
    __shared__ int sh_ids[NROWS];
    __shared__ int sh_order[NROWS];
    __shared__ int sh_cnt[NBINS];
    __shared__ int sh_last[LSEQ];
    __shared__ int sh_nb;
    if (tid < NROWS) sh_ids[tid] = ids[tid];
    for (int k = tid; k < NBINS; k += 256) sh_cnt[k] = 0;
    if (tid == 0) sh_nb = 0;
    __syncthreads();
    if (tid < NROWS) {
      const int my = sh_ids[tid];
      int rank = 0, first = 1;
      for (int j = 0; j < NROWS; ++j) {
        const int v = sh_ids[j];
        if (v < my || (v == my && j < tid)) rank++;
        if (v == my && j < tid) first = 0;
      }
      sh_order[rank] = tid;
      if (first) atomicAdd(&sh_nb, 1);
    }
    __syncthreads();
    const int nb = sh_nb;
    const int days = NROWS / nb;
    if (s == 0) {
      if (tid < NROWS) meta[tid] = sh_order[tid];
      if (tid == 0) meta[NROWS] = days;
    }
    const int lastRow = sh_order[s * days + days - 1];
    if (tid < LSEQ) sh_last[tid] = seq[lastRow * LSEQ + tid];
    __syncthreads();
    if (tid < LSEQ - 1) {
      const float v = dm[(size_t)(sh_last[tid] - 1) * N_POI + (sh_last[tid + 1] - 1)];
      int si = (int)ceilf(2.0f * v);
      si = min(max(si, 0), 101);
      atomicAdd(&sh_cnt[si], 1);
    }
    __syncthreads();
    const float inv = 1.0f / (float)(LSEQ - 1);
    for (int k = tid; k < 128; k += 256) {
      const float wv = (k < NBINS) ? (float)sh_cnt[k] * inv : 0.0f;
      tfp[s * 128 + k] = wv;
      tbu[s * 128 + k] = bf16bits(wv);
    }
  }
}

// ---------------------------------------------------------------------------
// K2: per (sample, 64-row tile): rowsum = hist_T·t - t[bucket[i,i]] + 1,
// r = rsqrt; Y1^T[d][i] = bf16(r_i * poi_emb[i][d]) written as uint4 pairs.
// ---------------------------------------------------------------------------
__global__ __launch_bounds__(256) void k_rows(const float* __restrict__ hist,
                                              const float* __restrict__ tfp,
                                              const u8* __restrict__ bucket,
                                              const float* __restrict__ poi,
                                              float* __restrict__ rbuf,
                                              ushort_t* __restrict__ y1t) {
  const int s = blockIdx.y, i0 = blockIdx.x * 64, tid = threadIdx.x;
  __shared__ float tl[NBINS];
  __shared__ float poiS[64 * 68];
  __shared__ float riS[64];
  for (int k = tid; k < NBINS; k += 256) tl[k] = tfp[s * 128 + k];
  for (int f = tid; f < 1024; f += 256) {
    const int r = f >> 4, c4 = (f & 15) * 4;
    *(float4*)&poiS[r * 68 + c4] = *(const float4*)(poi + (size_t)(i0 + 1 + r) * 64 + c4);
  }
  __syncthreads();
  if (tid < 64) {
    const int i = i0 + tid;
    float dot = 0.f;
#pragma unroll 6
    for (int k = 0; k < NBINS; ++k) dot += hist[(size_t)k * N_POI + i] * tl[k];
    const int bii = bucket[(size_t)i * N_POI + i];
    const float ri = rsqrtf(dot - tl[bii] + 1.0f);  // diag W[i,i]=1 override
    riS[tid] = ri;
    rbuf[s * N_POI + i] = ri;
  }
  __syncthreads();
  const int d = tid >> 2, iq = (tid & 3) * 16;
  u32 pk[8];
#pragma unroll
  for (int j = 0; j < 8; ++j) {
    const int ia = iq + 2 * j;
    const u32 lo = bf16bits(riS[ia] * poiS[ia * 68 + d]);
    const u32 hi = bf16bits(riS[ia + 1] * poiS[(ia + 1) * 68 + d]);
    pk[j] = lo | (hi << 16);
  }
  ushort_t* dst = y1t + ((size_t)s * 64 + d) * N_POI + i0 + iq;
  uint4 o0 = {pk[0], pk[1], pk[2], pk[3]};
  uint4 o1 = {pk[4], pk[5], pk[6], pk[7]};
  *(uint4*)dst = o0;
  *(uint4*)(dst + 8) = o1;
}

// ---------------------------------------------------------------------------
// K3: GCN layer partial GEMM, M-split x2 vs round 5: 64 rows/block (1 mt/wave),
// grid (64 rb, KCr, NB) = 1536 blocks @ KCr=3 -> 6 blocks/CU, 24 waves/CU.
// Split-K width KCr is ws-limited (~3); M-split needs NO extra workspace.
// A = t[bucket] (diag=1) from bank-replicated LDS LUT; Y^T staged in LDS.
// __launch_bounds__(256) ONLY — (256,7) caused scratch spills (round 3/4:
// VGPR 60->36, +500MB HBM spill traffic, 3x dur). No device atomics in
// epilogue (round 3: ~530MB HBM RMW traffic).
// ---------------------------------------------------------------------------
__global__ __launch_bounds__(256) void k_layer(
    const u8* __restrict__ bucket, const u32* __restrict__ tbu,
    const ushort_t* __restrict__ yin, ushort_t* __restrict__ part, int KCr) {
  const int rb = blockIdx.x, kc = blockIdx.y, s = blockIdx.z;
  const int tid = threadIdx.x;
  const int lane = tid & 63, w = tid >> 6;
  const int loff = tid & 31;

  __shared__ u32 trep[NBINS * 32];  // bank-replicated LUT (bank == lane%32)
  __shared__ ushort_t Yt[64 * 72];  // Y^T tile [d][k], stride 72

  for (int idx = tid; idx < NBINS * 32; idx += 256)
    trep[idx] = tbu[s * 128 + (idx >> 5)];

  const int gi0 = rb * 64;
  const int r0 = gi0 + w * 16 + (lane & 15);  // wave w owns rows [gi0+16w, +16)
  const u8* brow = bucket + (size_t)r0 * N_POI;
  const int kq = (lane >> 4) * 8;

  const ushort_t* ybase = yin + (size_t)s * 64 * N_POI;
  const int dA = tid >> 3, dB = 32 + (tid >> 3), sg = tid & 7;

  const int kt0 = (kc * 64) / KCr, kt1 = ((kc + 1) * 64) / KCr;

  f32x4 acc[4];
#pragma unroll
  for (int nt = 0; nt < 4; ++nt) acc[nt] = (f32x4){0.f, 0.f, 0.f, 0.f};

  // prefetch tile kt0
  uint4 yA = *(const uint4*)(ybase + (size_t)dA * N_POI + kt0 * 64 + sg * 8);
  uint4 yB = *(const uint4*)(ybase + (size_t)dB * N_POI + kt0 * 64 + sg * 8);
  uint2 bpre[2];
#pragma unroll
  for (int ks = 0; ks < 2; ++ks)
    bpre[ks] = *(const uint2*)(brow + kt0 * 64 + ks * 32 + kq);
  __syncthreads();  // trep ready

  for (int kt = kt0; kt < kt1; ++kt) {
    *(uint4*)&Yt[dA * 72 + sg * 8] = yA;
    *(uint4*)&Yt[dB * 72 + sg * 8] = yB;
    __syncthreads();

    uint2 bc[2];
#pragma unroll
    for (int q = 0; q < 2; ++q) bc[q] = bpre[q];

    if (kt < kt1 - 1) {  // prefetch next tile
      const int k0n = (kt + 1) * 64;
      yA = *(const uint4*)(ybase + (size_t)dA * N_POI + k0n + sg * 8);
      yB = *(const uint4*)(ybase + (size_t)dB * N_POI + k0n + sg * 8);
#pragma unroll
      for (int ks = 0; ks < 2; ++ks)
        bpre[ks] = *(const uint2*)(brow + k0n + ks * 32 + kq);
    }

    const int k0 = kt * 64;
    bf16x8 afr[2];
#pragma unroll
    for (int ks = 0; ks < 2; ++ks) {
      const uint2 bb = bc[ks];
      u32 tv[8];
#pragma unroll
      for (int e = 0; e < 4; ++e) tv[e]     = trep[((bb.x >> (8 * e)) & 255u) * 32 + loff];
#pragma unroll
      for (int e = 0; e < 4; ++e) tv[4 + e] = trep[((bb.y >> (8 * e)) & 255u) * 32 + loff];
      const int col0 = k0 + ks * 32 + kq;
      const u32 de = (u32)(r0 - col0);
      if (de < 8u) {  // diagonal A[i,i] = 1.0
#pragma unroll
        for (int e = 0; e < 8; ++e)
          if (de == (u32)e) tv[e] = 0x3F80u;
      }
      uint4 pk;
      pk.x = tv[0] | (tv[1] << 16);
      pk.y = tv[2] | (tv[3] << 16);
      pk.z = tv[4] | (tv[5] << 16);
      pk.w = tv[6] | (tv[7] << 16);
      union { uint4 u; bf16x8 v; } cvt;
      cvt.u = pk;
      afr[ks] = cvt.v;
    }

#pragma unroll
    for (int ks = 0; ks < 2; ++ks) {
#pragma unroll
      for (int nt = 0; nt < 4; ++nt) {
        union { uint4 u; bf16x8 v; } bu;
        bu.u = *(const uint4*)&Yt[(nt * 16 + (lane & 15)) * 72 + ks * 32 + kq];
        acc[nt] = __builtin_amdgcn_mfma_f32_16x16x32_bf16(afr[ks], bu.v, acc[nt], 0, 0, 0);
      }
    }
    __syncthreads();
  }

  // epilogue: bf16 partials. C/D layout: col = lane&15, row = (lane>>4)*4+e
#pragma unroll
  for (int e = 0; e < 4; ++e) {
    const int row = gi0 + w * 16 + (lane >> 4) * 4 + e;
#pragma unroll
    for (int nt = 0; nt < 4; ++nt) {
      const int col = nt * 16 + (lane & 15);
      part[(((size_t)kc * NB + s) * N_POI + row) * 64 + col] =
          (ushort_t)bf16bits(acc[nt][e]);
    }
  }
}

// ---------------------------------------------------------------------------
// K3b: reduce KCr partials, t = tanh(r*x).
// layer 1: table = poi_emb + t (fp32); y2t^T = bf16(r*t) via LDS transpose.
// layer 2: table += t.
// ---------------------------------------------------------------------------
__global__ __launch_bounds__(256) void k_reduce(
    const ushort_t* __restrict__ part, const float* __restrict__ rbuf,
    const float* __restrict__ poi, float* __restrict__ table,
    ushort_t* __restrict__ y2t, int layer, int KCr) {
  const int it = blockIdx.x, s = blockIdx.y, tid = threadIdx.x;
  const size_t chunk = (size_t)NB * N_POI * 64;
  __shared__ ushort_t Tt[64 * 72];
#pragma unroll
  for (int j = 0; j < 2; ++j) {
    const int s2 = tid + j * 256;
    const int iloc = s2 >> 3, d0 = (s2 & 7) * 8;
    const int i = it * 64 + iloc;
    const size_t po = ((size_t)s * N_POI + i) * 64 + d0;
    float x[8] = {0.f, 0.f, 0.f, 0.f, 0.f, 0.f, 0.f, 0.f};
    for (int kc = 0; kc < KCr; ++kc) {
      const uint4 p = *(const uint4*)(part + kc * chunk + po);
      const u32* a = (const u32*)&p;
#pragma unroll
      for (int q = 0; q < 4; ++q) {
        x[2 * q]     += __uint_as_float(a[q] << 16);
        x[2 * q + 1] += __uint_as_float(a[q] & 0xFFFF0000u);
      }
    }
    const float ri = rbuf[s * N_POI + i];
    float t[8];
#pragma unroll
    for (int e = 0; e < 8; ++e) t[e] = tanhf(ri * x[e]);
    float* trow = table + po;
    if (layer == 1) {
      const float* prow = poi + (size_t)(i + 1) * 64 + d0;
      const float4 pz0 = *(const float4*)prow;
      const float4 pz1 = *(const float4*)(prow + 4);
      float4 o0 = {pz0.x + t[0], pz0.y + t[1], pz0.z + t[2], pz0.w + t[3]};
      float4 o1 = {pz1.x + t[4], pz1.y + t[5], pz1.z + t[6], pz1.w + t[7]};
      *(float4*)trow = o0;
      *(float4*)(trow + 4) = o1;
#pragma unroll
      for (int e = 0; e < 8; ++e)
        Tt[(d0 + e) * 72 + iloc] = (ushort_t)bf16bits(ri * t[e]);
    } else {
      float4 c0 = *(const float4*)trow;
      float4 c1 = *(const float4*)(trow + 4);
      c0.x += t[0]; c0.y += t[1]; c0.z += t[2]; c0.w += t[3];
      c1.x += t[4]; c1.y += t[5]; c1.z += t[6]; c1.w += t[7];
      *(float4*)trow = c0;
      *(float4*)(trow + 4) = c1;
    }
  }
  if (layer == 1) {
    __syncthreads();
    const int d = tid >> 2, i0 = (tid & 3) * 16;
    uint4 a = *(const uint4*)&Tt[d * 72 + i0];
    uint4 b = *(const uint4*)&Tt[d * 72 + i0 + 8];
    ushort_t* dst = y2t + ((size_t)s * 64 + d) * N_POI + it * 64 + i0;
    *(uint4*)dst = a;
    *(uint4*)(dst + 8) = b;
  }
}

// ---------------------------------------------------------------------------
// K4: gather output rows: out[r][p][:] = table_g[seq[order[r]][p]] * sqrt(64)
// ---------------------------------------------------------------------------
__global__ __launch_bounds__(256) void k_gather(const int* __restrict__ seq,
                                                const int* __restrict__ meta,
                                                const float* __restrict__ table,
                                                const float* __restrict__ poi,
                                                float* __restrict__ out) {
  const int r = blockIdx.x;
  const int p = blockIdx.y * 4 + (threadIdx.x >> 6);
  const int d = threadIdx.x & 63;
  const int days = meta[NROWS];
  const int srcrow = meta[r];
  const int g = r / days;
  const int id = seq[srcrow * LSEQ + p];
  const float v = (id == 0) ? poi[d]
                            : table[((size_t)g * N_POI + (id - 1)) * 64 + d];
  out[((size_t)r * LSEQ + p) * 64 + d] = v * 8.0f;
}

// ---------------------------------------------------------------------------
extern "C" void kernel_launch(void* const* d_in, const int* in_sizes, int n_in,
                              void* d_out, int out_size, void* d_ws, size_t ws_size,
                              hipStream_t stream) {
  (void)in_sizes; (void)n_in; (void)out_size;
  const float* poi = (const float*)d_in[0];  // (4097, 64) f32
  const float* dm  = (const float*)d_in[1];  // (4096, 4096) f32
  const int*   seq = (const int*)d_in[2];    // (32, 64) i32
  const int*   ids = (const int*)d_in[3];    // (32,) i32
  // d_in[4]: GCN_layer_num (== 2 per setup_inputs)

  char* ws = (char*)d_ws;
  size_t off = 0;
  auto carve = [&](size_t bytes) {
    char* p = ws + off;
    off += (bytes + 255) & ~(size_t)255;
    return p;
  };
  u8*       bucket = (u8*)carve((size_t)N_POI * N_POI);            // 16.78 MB
  float*    hist   = (float*)carve((size_t)NBINS * N_POI * 4);     // 1.67 MB (transposed)
  float*    tfp    = (float*)carve((size_t)NB * 128 * 4);
  u32*      tbu    = (u32*)carve((size_t)NB * 128 * 4);
  float*    rbuf   = (float*)carve((size_t)NB * N_POI * 4);
  // table (fp32) aliases y1t (bf16): y1t dead after k_layer L1; table first
  // written by k_reduce L1 (later in stream).
  float*    table  = (float*)carve((size_t)NB * N_POI * 64 * 4);     // 8.39 MB
  ushort_t* y1t    = (ushort_t*)table;
  ushort_t* y2t    = (ushort_t*)carve((size_t)NB * 64 * N_POI * 2);  // 4.19 MB
  int*      meta   = (int*)carve(256);
  // part carved LAST: size determines runtime KCr (split-K width).
  const size_t chunk_bytes = (size_t)NB * N_POI * 64 * 2;            // 4.19 MB/chunk
  int KCr = (int)((ws_size > off) ? ((ws_size - off) / chunk_bytes) : 1);
  if (KCr > KCMAX) KCr = KCMAX;
  if (KCr < 1) KCr = 1;
  ushort_t* part = (ushort_t*)carve((size_t)KCr * chunk_bytes);

  k_bucket_sample<<<2048 + NB, 256, 0, stream>>>(dm, bucket, hist, ids, seq, tfp, tbu, meta);
  k_rows<<<dim3(64, NB), 256, 0, stream>>>(hist, tfp, bucket, poi, rbuf, y1t);
  k_layer<<<dim3(64, KCr, NB), 256, 0, stream>>>(bucket, tbu, y1t, part, KCr);
  k_reduce<<<dim3(64, NB), 256, 0, stream>>>(part, rbuf, poi, table, y2t, 1, KCr);
  k_layer<<<dim3(64, KCr, NB), 256, 0, stream>>>(bucket, tbu, y2t, part, KCr);
  k_reduce<<<dim3(64, NB), 256, 0, stream>>>(part, rbuf, poi, table, y2t, 2, KCr);
  k_gather<<<dim3(NROWS, 16), 256, 0, stream>>>(seq, meta, table, poi, (float*)d_out);
}

// Round 7
// 227.059 us; speedup vs baseline: 1.0457x; 1.0457x over previous
//
#include <hip/hip_runtime.h>
#include <hip/hip_bf16.h>
#include <math.h>

typedef __bf16 bf16x8 __attribute__((ext_vector_type(8)));
typedef float  f32x4  __attribute__((ext_vector_type(4)));
typedef unsigned short ushort_t;
typedef unsigned char  u8;
typedef unsigned int   u32;

#define N_POI 4096
#define NB    8
#define NDAYS 4
#define LSEQ  64
#define NROWS 32   // NB*NDAYS
#define NBINS 102  // 101 intervals + 1 pad/clamp slot
#define KCMAX 7    // split-K width cap (runtime KCr is ws-limited, ~3)

static __device__ __forceinline__ u32 bf16bits(float f) {
  u32 x = __float_as_uint(f);
  return ((x + 0x7FFFu + ((x >> 16) & 1u)) >> 16) & 0xFFFFu;  // RTNE
}

// ---------------------------------------------------------------------------
// K1: fused bucketize + per-sample setup.
// Blocks [0,2048): 2 dm rows each -> uint8 buckets (side='right' == floor(2v)+1)
//   written as uint4 (16 bytes/thread), + per-row histograms (transposed).
// Blocks [2048, 2048+NB): per-sample argsort/spans/bincount weight tables.
// ---------------------------------------------------------------------------
__global__ __launch_bounds__(256) void k_bucket_sample(
    const float* __restrict__ dm, u8* __restrict__ bucket,
    float* __restrict__ hist, const int* __restrict__ ids,
    const int* __restrict__ seq, float* __restrict__ tfp,
    u32* __restrict__ tbu, int* __restrict__ meta) {
  const int tid = threadIdx.x;
  if (blockIdx.x < 2048) {
    const int row0 = blockIdx.x * 2;
    __shared__ int h[2][NBINS];
    for (int k = tid; k < 2 * NBINS; k += 256) ((int*)h)[k] = 0;
    __syncthreads();
#pragma unroll
    for (int r = 0; r < 2; ++r) {
      const float4* drow = (const float4*)(dm + (size_t)(row0 + r) * N_POI);
      uint4* brow = (uint4*)(bucket + (size_t)(row0 + r) * N_POI);
      const int j4 = tid * 4;  // this thread: 16 consecutive elements
      const float4 v0 = drow[j4];
      const float4 v1 = drow[j4 + 1];
      const float4 v2 = drow[j4 + 2];
      const float4 v3 = drow[j4 + 3];
      u32 wq[4];
      const float4 vv[4] = {v0, v1, v2, v3};
#pragma unroll
      for (int q = 0; q < 4; ++q) {
        const int b0 = min((int)(2.0f * vv[q].x) + 1, 101);
        const int b1 = min((int)(2.0f * vv[q].y) + 1, 101);
        const int b2 = min((int)(2.0f * vv[q].z) + 1, 101);
        const int b3 = min((int)(2.0f * vv[q].w) + 1, 101);
        atomicAdd(&h[r][b0], 1); atomicAdd(&h[r][b1], 1);
        atomicAdd(&h[r][b2], 1); atomicAdd(&h[r][b3], 1);
        wq[q] = (u32)b0 | ((u32)b1 << 8) | ((u32)b2 << 16) | ((u32)b3 << 24);
      }
      uint4 pk = {wq[0], wq[1], wq[2], wq[3]};
      brow[tid] = pk;
    }
    __syncthreads();
    for (int k = tid; k < NBINS; k += 256) {
      hist[(size_t)k * N_POI + row0]     = (float)h[0][k];
      hist[(size_t)k * N_POI + row0 + 1] = (float)h[1][k];
    }
  } else {
    const int s = blockIdx.x - 2048;
    __shared__ int sh_ids[NROWS];
    __shared__ int sh_order[NROWS];
    __shared__ int sh_cnt[NBINS];
    __shared__ int sh_last[LSEQ];
    __shared__ int sh_nb;
    if (tid < NROWS) sh_ids[tid] = ids[tid];
    for (int k = tid; k < NBINS; k += 256) sh_cnt[k] = 0;
    if (tid == 0) sh_nb = 0;
    __syncthreads();
    if (tid < NROWS) {
      const int my = sh_ids[tid];
      int rank = 0, first = 1;
      for (int j = 0; j < NROWS; ++j) {
        const int v = sh_ids[j];
        if (v < my || (v == my && j < tid)) rank++;
        if (v == my && j < tid) first = 0;
      }
      sh_order[rank] = tid;
      if (first) atomicAdd(&sh_nb, 1);
    }
    __syncthreads();
    const int nb = sh_nb;
    const int days = NROWS / nb;
    if (s == 0) {
      if (tid < NROWS) meta[tid] = sh_order[tid];
      if (tid == 0) meta[NROWS] = days;
    }
    const int lastRow = sh_order[s * days + days - 1];
    if (tid < LSEQ) sh_last[tid] = seq[lastRow * LSEQ + tid];
    __syncthreads();
    if (tid < LSEQ - 1) {
      const float v = dm[(size_t)(sh_last[tid] - 1) * N_POI + (sh_last[tid + 1] - 1)];
      int si = (int)ceilf(2.0f * v);
      si = min(max(si, 0), 101);
      atomicAdd(&sh_cnt[si], 1);
    }
    __syncthreads();
    const float inv = 1.0f / (float)(LSEQ - 1);
    for (int k = tid; k < 128; k += 256) {
      const float wv = (k < NBINS) ? (float)sh_cnt[k] * inv : 0.0f;
      tfp[s * 128 + k] = wv;
      tbu[s * 128 + k] = bf16bits(wv);
    }
  }
}

// ---------------------------------------------------------------------------
// K2: per (sample, 64-row tile): rowsum = hist_T·t - t[bucket[i,i]] + 1,
// r = rsqrt; Y1^T[d][i] = bf16(r_i * poi_emb[i][d]) written as uint4 pairs.
// ---------------------------------------------------------------------------
__global__ __launch_bounds__(256) void k_rows(const float* __restrict__ hist,
                                              const float* __restrict__ tfp,
                                              const u8* __restrict__ bucket,
                                              const float* __restrict__ poi,
                                              float* __restrict__ rbuf,
                                              ushort_t* __restrict__ y1t) {
  const int s = blockIdx.y, i0 = blockIdx.x * 64, tid = threadIdx.x;
  __shared__ float tl[NBINS];
  __shared__ float poiS[64 * 68];
  __shared__ float riS[64];
  for (int k = tid; k < NBINS; k += 256) tl[k] = tfp[s * 128 + k];
  for (int f = tid; f < 1024; f += 256) {
    const int r = f >> 4, c4 = (f & 15) * 4;
    *(float4*)&poiS[r * 68 + c4] = *(const float4*)(poi + (size_t)(i0 + 1 + r) * 64 + c4);
  }
  __syncthreads();
  if (tid < 64) {
    const int i = i0 + tid;
    float dot = 0.f;
#pragma unroll 6
    for (int k = 0; k < NBINS; ++k) dot += hist[(size_t)k * N_POI + i] * tl[k];
    const int bii = bucket[(size_t)i * N_POI + i];
    const float ri = rsqrtf(dot - tl[bii] + 1.0f);  // diag W[i,i]=1 override
    riS[tid] = ri;
    rbuf[s * N_POI + i] = ri;
  }
  __syncthreads();
  const int d = tid >> 2, iq = (tid & 3) * 16;
  u32 pk[8];
#pragma unroll
  for (int j = 0; j < 8; ++j) {
    const int ia = iq + 2 * j;
    const u32 lo = bf16bits(riS[ia] * poiS[ia * 68 + d]);
    const u32 hi = bf16bits(riS[ia + 1] * poiS[(ia + 1) * 68 + d]);
    pk[j] = lo | (hi << 16);
  }
  ushort_t* dst = y1t + ((size_t)s * 64 + d) * N_POI + i0 + iq;
  uint4 o0 = {pk[0], pk[1], pk[2], pk[3]};
  uint4 o1 = {pk[4], pk[5], pk[6], pk[7]};
  *(uint4*)dst = o0;
  *(uint4*)(dst + 8) = o1;
}

// ---------------------------------------------------------------------------
// K3: GCN layer partial GEMM. Round-5 shape restored (128 rows/block, 2 mt/wave
// — round 6's 64-row split raised LDS cost/row from 9.6 to 12 cyc and doubled
// bank conflicts) + DOUBLE-BUFFERED Y tile: one barrier per ktile instead of
// two. Grid (32 rb, KCr, NB) = 768 @ KCr=3 -> 3 blocks/CU balanced.
// LDS: trep 12.75KB + 2x9KB Yt = 30.8KB -> 3 blocks/CU fit (92KB < 160KB).
// __launch_bounds__(256) ONLY — (256,7) caused scratch spills (rounds 3/4).
// No device atomics in epilogue (round 3: ~530MB HBM RMW traffic).
// ---------------------------------------------------------------------------
__global__ __launch_bounds__(256) void k_layer(
    const u8* __restrict__ bucket, const u32* __restrict__ tbu,
    const ushort_t* __restrict__ yin, ushort_t* __restrict__ part, int KCr) {
  const int rb = blockIdx.x, kc = blockIdx.y, s = blockIdx.z;
  const int tid = threadIdx.x;
  const int lane = tid & 63, w = tid >> 6;
  const int loff = tid & 31;

  __shared__ u32 trep[NBINS * 32];     // bank-replicated LUT (bank == lane%32)
  __shared__ ushort_t Yt[2][64 * 72];  // double-buffered Y^T tile [d][k], stride 72

  for (int idx = tid; idx < NBINS * 32; idx += 256)
    trep[idx] = tbu[s * 128 + (idx >> 5)];

  const int gi0 = rb * 128;
  const int r0 = gi0 + w * 32 + (lane & 15);
  const u8* brow0 = bucket + (size_t)r0 * N_POI;
  const u8* brow1 = brow0 + (size_t)16 * N_POI;
  const int kq = (lane >> 4) * 8;

  const ushort_t* ybase = yin + (size_t)s * 64 * N_POI;
  const int dA = tid >> 3, dB = 32 + (tid >> 3), sg = tid & 7;

  const int kt0 = (kc * 64) / KCr, kt1 = ((kc + 1) * 64) / KCr;

  f32x4 acc[2][4];
#pragma unroll
  for (int mt = 0; mt < 2; ++mt)
#pragma unroll
    for (int nt = 0; nt < 4; ++nt) acc[mt][nt] = (f32x4){0.f, 0.f, 0.f, 0.f};

  // prefetch tile kt0 into registers
  uint4 yA = *(const uint4*)(ybase + (size_t)dA * N_POI + kt0 * 64 + sg * 8);
  uint4 yB = *(const uint4*)(ybase + (size_t)dB * N_POI + kt0 * 64 + sg * 8);
  uint2 bpre[4];
#pragma unroll
  for (int mt = 0; mt < 2; ++mt)
#pragma unroll
    for (int ks = 0; ks < 2; ++ks)
      bpre[mt * 2 + ks] = *(const uint2*)((mt ? brow1 : brow0) + kt0 * 64 + ks * 32 + kq);
  __syncthreads();  // trep ready

  int p = 0;
  for (int kt = kt0; kt < kt1; ++kt) {
    // Stage current tile into buffer p. Safe without a pre-barrier: other
    // waves still computing iter kt-1 read buffer p^1; buffer p was last
    // read in iter kt-2, whose readers passed barrier(kt-1) first.
    *(uint4*)&Yt[p][dA * 72 + sg * 8] = yA;
    *(uint4*)&Yt[p][dB * 72 + sg * 8] = yB;
    __syncthreads();  // Yt[p] ready for all waves

    uint2 bc[4];
#pragma unroll
    for (int q = 0; q < 4; ++q) bc[q] = bpre[q];

    if (kt < kt1 - 1) {  // prefetch next tile into registers
      const int k0n = (kt + 1) * 64;
      yA = *(const uint4*)(ybase + (size_t)dA * N_POI + k0n + sg * 8);
      yB = *(const uint4*)(ybase + (size_t)dB * N_POI + k0n + sg * 8);
#pragma unroll
      for (int mt = 0; mt < 2; ++mt)
#pragma unroll
        for (int ks = 0; ks < 2; ++ks)
          bpre[mt * 2 + ks] = *(const uint2*)((mt ? brow1 : brow0) + k0n + ks * 32 + kq);
    }

    const int k0 = kt * 64;
    bf16x8 afr[2][2];
#pragma unroll
    for (int mt = 0; mt < 2; ++mt) {
#pragma unroll
      for (int ks = 0; ks < 2; ++ks) {
        const uint2 bb = bc[mt * 2 + ks];
        u32 tv[8];
#pragma unroll
        for (int e = 0; e < 4; ++e) tv[e]     = trep[((bb.x >> (8 * e)) & 255u) * 32 + loff];
#pragma unroll
        for (int e = 0; e < 4; ++e) tv[4 + e] = trep[((bb.y >> (8 * e)) & 255u) * 32 + loff];
        const int grow = r0 + mt * 16;
        const int col0 = k0 + ks * 32 + kq;
        const u32 de = (u32)(grow - col0);
        if (de < 8u) {  // diagonal A[i,i] = 1.0
#pragma unroll
          for (int e = 0; e < 8; ++e)
            if (de == (u32)e) tv[e] = 0x3F80u;
        }
        uint4 pk;
        pk.x = tv[0] | (tv[1] << 16);
        pk.y = tv[2] | (tv[3] << 16);
        pk.z = tv[4] | (tv[5] << 16);
        pk.w = tv[6] | (tv[7] << 16);
        union { uint4 u; bf16x8 v; } cvt;
        cvt.u = pk;
        afr[mt][ks] = cvt.v;
      }
    }

#pragma unroll
    for (int ks = 0; ks < 2; ++ks) {
#pragma unroll
      for (int nt = 0; nt < 4; ++nt) {
        union { uint4 u; bf16x8 v; } bu;
        bu.u = *(const uint4*)&Yt[p][(nt * 16 + (lane & 15)) * 72 + ks * 32 + kq];
        acc[0][nt] = __builtin_amdgcn_mfma_f32_16x16x32_bf16(afr[0][ks], bu.v, acc[0][nt], 0, 0, 0);
        acc[1][nt] = __builtin_amdgcn_mfma_f32_16x16x32_bf16(afr[1][ks], bu.v, acc[1][nt], 0, 0, 0);
      }
    }
    p ^= 1;  // no trailing barrier: next iter writes the other buffer
  }

  // epilogue: bf16 partials. C/D layout: col = lane&15, row = (lane>>4)*4+e
#pragma unroll
  for (int mt = 0; mt < 2; ++mt) {
#pragma unroll
    for (int e = 0; e < 4; ++e) {
      const int row = gi0 + w * 32 + mt * 16 + (lane >> 4) * 4 + e;
#pragma unroll
      for (int nt = 0; nt < 4; ++nt) {
        const int col = nt * 16 + (lane & 15);
        part[(((size_t)kc * NB + s) * N_POI + row) * 64 + col] =
            (ushort_t)bf16bits(acc[mt][nt][e]);
      }
    }
  }
}

// ---------------------------------------------------------------------------
// K3b: reduce KCr partials, t = tanh(r*x).
// layer 1: table = poi_emb + t (fp32); y2t^T = bf16(r*t) via LDS transpose.
// layer 2: table += t.
// ---------------------------------------------------------------------------
__global__ __launch_bounds__(256) void k_reduce(
    const ushort_t* __restrict__ part, const float* __restrict__ rbuf,
    const float* __restrict__ poi, float* __restrict__ table,
    ushort_t* __restrict__ y2t, int layer, int KCr) {
  const int it = blockIdx.x, s = blockIdx.y, tid = threadIdx.x;
  const size_t chunk = (size_t)NB * N_POI * 64;
  __shared__ ushort_t Tt[64 * 72];
#pragma unroll
  for (int j = 0; j < 2; ++j) {
    const int s2 = tid + j * 256;
    const int iloc = s2 >> 3, d0 = (s2 & 7) * 8;
    const int i = it * 64 + iloc;
    const size_t po = ((size_t)s * N_POI + i) * 64 + d0;
    float x[8] = {0.f, 0.f, 0.f, 0.f, 0.f, 0.f, 0.f, 0.f};
    for (int kc = 0; kc < KCr; ++kc) {
      const uint4 p = *(const uint4*)(part + kc * chunk + po);
      const u32* a = (const u32*)&p;
#pragma unroll
      for (int q = 0; q < 4; ++q) {
        x[2 * q]     += __uint_as_float(a[q] << 16);
        x[2 * q + 1] += __uint_as_float(a[q] & 0xFFFF0000u);
      }
    }
    const float ri = rbuf[s * N_POI + i];
    float t[8];
#pragma unroll
    for (int e = 0; e < 8; ++e) t[e] = tanhf(ri * x[e]);
    float* trow = table + po;
    if (layer == 1) {
      const float* prow = poi + (size_t)(i + 1) * 64 + d0;
      const float4 pz0 = *(const float4*)prow;
      const float4 pz1 = *(const float4*)(prow + 4);
      float4 o0 = {pz0.x + t[0], pz0.y + t[1], pz0.z + t[2], pz0.w + t[3]};
      float4 o1 = {pz1.x + t[4], pz1.y + t[5], pz1.z + t[6], pz1.w + t[7]};
      *(float4*)trow = o0;
      *(float4*)(trow + 4) = o1;
#pragma unroll
      for (int e = 0; e < 8; ++e)
        Tt[(d0 + e) * 72 + iloc] = (ushort_t)bf16bits(ri * t[e]);
    } else {
      float4 c0 = *(const float4*)trow;
      float4 c1 = *(const float4*)(trow + 4);
      c0.x += t[0]; c0.y += t[1]; c0.z += t[2]; c0.w += t[3];
      c1.x += t[4]; c1.y += t[5]; c1.z += t[6]; c1.w += t[7];
      *(float4*)trow = c0;
      *(float4*)(trow + 4) = c1;
    }
  }
  if (layer == 1) {
    __syncthreads();
    const int d = tid >> 2, i0 = (tid & 3) * 16;
    uint4 a = *(const uint4*)&Tt[d * 72 + i0];
    uint4 b = *(const uint4*)&Tt[d * 72 + i0 + 8];
    ushort_t* dst = y2t + ((size_t)s * 64 + d) * N_POI + it * 64 + i0;
    *(uint4*)dst = a;
    *(uint4*)(dst + 8) = b;
  }
}

// ---------------------------------------------------------------------------
// K4: gather output rows: out[r][p][:] = table_g[seq[order[r]][p]] * sqrt(64)
// ---------------------------------------------------------------------------
__global__ __launch_bounds__(256) void k_gather(const int* __restrict__ seq,
                                                const int* __restrict__ meta,
                                                const float* __restrict__ table,
                                                const float* __restrict__ poi,
                                                float* __restrict__ out) {
  const int r = blockIdx.x;
  const int p = blockIdx.y * 4 + (threadIdx.x >> 6);
  const int d = threadIdx.x & 63;
  const int days = meta[NROWS];
  const int srcrow = meta[r];
  const int g = r / days;
  const int id = seq[srcrow * LSEQ + p];
  const float v = (id == 0) ? poi[d]
                            : table[((size_t)g * N_POI + (id - 1)) * 64 + d];
  out[((size_t)r * LSEQ + p) * 64 + d] = v * 8.0f;
}

// ---------------------------------------------------------------------------
extern "C" void kernel_launch(void* const* d_in, const int* in_sizes, int n_in,
                              void* d_out, int out_size, void* d_ws, size_t ws_size,
                              hipStream_t stream) {
  (void)in_sizes; (void)n_in; (void)out_size;
  const float* poi = (const float*)d_in[0];  // (4097, 64) f32
  const float* dm  = (const float*)d_in[1];  // (4096, 4096) f32
  const int*   seq = (const int*)d_in[2];    // (32, 64) i32
  const int*   ids = (const int*)d_in[3];    // (32,) i32
  // d_in[4]: GCN_layer_num (== 2 per setup_inputs)

  char* ws = (char*)d_ws;
  size_t off = 0;
  auto carve = [&](size_t bytes) {
    char* p = ws + off;
    off += (bytes + 255) & ~(size_t)255;
    return p;
  };
  u8*       bucket = (u8*)carve((size_t)N_POI * N_POI);            // 16.78 MB
  float*    hist   = (float*)carve((size_t)NBINS * N_POI * 4);     // 1.67 MB (transposed)
  float*    tfp    = (float*)carve((size_t)NB * 128 * 4);
  u32*      tbu    = (u32*)carve((size_t)NB * 128 * 4);
  float*    rbuf   = (float*)carve((size_t)NB * N_POI * 4);
  // table (fp32) aliases y1t (bf16): y1t dead after k_layer L1; table first
  // written by k_reduce L1 (later in stream).
  float*    table  = (float*)carve((size_t)NB * N_POI * 64 * 4);     // 8.39 MB
  ushort_t* y1t    = (ushort_t*)table;
  ushort_t* y2t    = (ushort_t*)carve((size_t)NB * 64 * N_POI * 2);  // 4.19 MB
  int*      meta   = (int*)carve(256);
  // part carved LAST: size determines runtime KCr (split-K width).
  const size_t chunk_bytes = (size_t)NB * N_POI * 64 * 2;            // 4.19 MB/chunk
  int KCr = (int)((ws_size > off) ? ((ws_size - off) / chunk_bytes) : 1);
  if (KCr > KCMAX) KCr = KCMAX;
  if (KCr < 1) KCr = 1;
  ushort_t* part = (ushort_t*)carve((size_t)KCr * chunk_bytes);

  k_bucket_sample<<<2048 + NB, 256, 0, stream>>>(dm, bucket, hist, ids, seq, tfp, tbu, meta);
  k_rows<<<dim3(64, NB), 256, 0, stream>>>(hist, tfp, bucket, poi, rbuf, y1t);
  k_layer<<<dim3(32, KCr, NB), 256, 0, stream>>>(bucket, tbu, y1t, part, KCr);
  k_reduce<<<dim3(64, NB), 256, 0, stream>>>(part, rbuf, poi, table, y2t, 1, KCr);
  k_layer<<<dim3(32, KCr, NB), 256, 0, stream>>>(bucket, tbu, y2t, part, KCr);
  k_reduce<<<dim3(64, NB), 256, 0, stream>>>(part, rbuf, poi, table, y2t, 2, KCr);
  k_gather<<<dim3(NROWS, 16), 256, 0, stream>>>(seq, meta, table, poi, (float*)d_out);
}